// Round 17
// baseline (410.431 us; speedup 1.0000x reference)
//
#include <hip/hip_runtime.h>

// LightGCN on MI355X, round 17.
// r1..r13: gather CSR, LDS-binned block-exclusive build, bf16 tables,
//          quad-edge + dual-row gather -> 419 us.
// r14: concurrent II+UI builds -> 410. r15: CHUNK 4096 FAILED (CAPE_UI sized by
//      edge-level sigma; UI randomness is user-level). r16: CAPE_UI 2048 -> 407,
//      but pass_a FLAT at ~96 us across Occ 26->53%: fixed serial chain =
//      per-(block,bucket) reservation atomics; 782 same-address L2 RMWs x 135ns
//      (r3 measurement) = 105 us. Occupancy can't fix a serialized RMW chain.
// r17: 8 sub-cursors per bucket (bcur[b*8+chunk&7], fixed 1/8 sub-regions):
//      chain 782 -> 98 (~13 us). Slot padding per sub-region keeps write amp 1.0.
//      pass_b iterates 8 sub-regions. Caps: II sub 1664 vs fill 1372 (8.3 sigma),
//      UI sub 512 vs 330 (6 sigma, user-level checked).

#define MM 100000
#define UU 50000
#define DD 64
#define RPB 256           // rows per coarse bucket
#define BSH 8
#define NBMAX 400
#define CHUNK 4096
#define KSUB 8            // sub-cursors per bucket
#define CAP_II 13312      // tmp stride (8B entries); sub-region 1664
#define CAP_UI 4096       // tmp stride UI; sub-region 512
#define CAPE_II 9216      // edges stride II
#define CAPE_UI 2048      // edges stride UI (user-level sigma margin, r16)

__device__ __forceinline__ unsigned short f2bf(float f) {
    unsigned int b = __float_as_uint(f);
    b += 0x7FFF + ((b >> 16) & 1);          // round-to-nearest-even
    return (unsigned short)(b >> 16);
}
// packed edge: (dst << 15) | (bf16(val) & 0x7FFF); val >= 0 so sign bit unused
__device__ __forceinline__ float pk_val(unsigned int w) {
    return __uint_as_float((w & 0x7FFFu) << 16);
}
__device__ __forceinline__ int pk_dst(unsigned int w) { return (int)(w >> 15); }

// ---- combined pass A: LDS binning + coalesced flush for BOTH graphs ----
__global__ void pass_a(const int* __restrict__ src_ii, const int* __restrict__ dst_ii,
                       const float* __restrict__ val_ii, int* __restrict__ bcur_ii,
                       int2* __restrict__ tmp_ii, int nnz_ii, int nb_ii, int nchunks_ii,
                       const int* __restrict__ src_ui, const int* __restrict__ dst_ui,
                       const float* __restrict__ val_ui, int* __restrict__ bcur_ui,
                       int2* __restrict__ tmp_ui, int nnz_ui, int nb_ui,
                       const unsigned char* __restrict__ filter) {
    extern __shared__ char smem[];
    int2* stage = (int2*)smem;                     // CHUNK entries (32 KB)
    int*  lcnt  = (int*)(smem + CHUNK * 8);
    int*  lbase = lcnt + NBMAX;
    int*  lcur  = lbase + NBMAX;
    int*  gbase = lcur + NBMAX;
    const bool is_ii = (blockIdx.x < (unsigned)nchunks_ii);
    const int chunk_id = is_ii ? blockIdx.x : (blockIdx.x - nchunks_ii);
    const int* __restrict__ src = is_ii ? src_ii : src_ui;
    const int* __restrict__ dst = is_ii ? dst_ii : dst_ui;
    const float* __restrict__ val = is_ii ? val_ii : val_ui;
    int* __restrict__ bcur = is_ii ? bcur_ii : bcur_ui;
    int2* __restrict__ tmp = is_ii ? tmp_ii : tmp_ui;
    const int nnz = is_ii ? nnz_ii : nnz_ui;
    const int nb  = is_ii ? nb_ii : nb_ui;
    const int cap = is_ii ? CAP_II : CAP_UI;
    const unsigned char* __restrict__ flt = is_ii ? nullptr : filter;
    const int ksub = chunk_id & (KSUB - 1);

    int t = threadIdx.x;
    for (int i = t; i < nb; i += blockDim.x) lcnt[i] = 0;
    __syncthreads();
    int beg = chunk_id * CHUNK, end = min(nnz, beg + CHUNK);
    for (int i = beg + t; i < end; i += blockDim.x) {
        int s = src[i];
        if (flt && !flt[s]) continue;
        atomicAdd(&lcnt[s >> BSH], 1);
    }
    __syncthreads();
    // wave 0: exclusive scan lcnt -> lbase
    if (t < 64) {
        int carry = 0;
        for (int g = 0; g < nb; g += 64) {
            int i = g + t;
            int v = (i < nb) ? lcnt[i] : 0;
            int incl = v;
            #pragma unroll
            for (int m = 1; m < 64; m <<= 1) {
                int u = __shfl_up(incl, m, 64);
                if (t >= m) incl += u;
            }
            if (i < nb) lbase[i] = carry + incl - v;
            carry += __shfl(incl, 63, 64);
        }
    }
    __syncthreads();
    // slot-granular reservation on the bucket's SUB-cursor (chain depth /KSUB)
    for (int i = t; i < nb; i += blockDim.x) {
        int c = lcnt[i];
        int slots = (c + 7) >> 3;
        int res = slots ? atomicAdd(&bcur[i * KSUB + ksub], slots) : 0;
        gbase[i] = i * cap + ksub * (cap >> 3) + res * 8;
        lcur[i] = lbase[i];
    }
    __syncthreads();
    // bin into LDS stage
    for (int i = beg + t; i < end; i += blockDim.x) {
        int s = src[i];
        if (flt && !flt[s]) continue;
        int b = s >> BSH;
        int pos = atomicAdd(&lcur[b], 1);
        stage[pos] = make_int2(dst[i] | ((s & (RPB - 1)) << 17), __float_as_int(val[i]));
    }
    __syncthreads();
    // coalesced flush: wave per bucket; pad tail slot with markers in-burst
    int lane = t & 63, wv = t >> 6;
    int nwv = blockDim.x >> 6;
    for (int i = wv; i < nb; i += nwv) {
        int c = lcnt[i], lb = lbase[i], gb = gbase[i];
        int cp = (c + 7) & ~7;
        for (int k = lane; k < cp; k += 64) {
            int2 e = (k < c) ? stage[lb + k] : make_int2(-1, 0);
            tmp[gb + k] = e;
        }
    }
}

// ---- combined pass B: per-bucket LDS sort over KSUB sub-regions ----
__global__ void pass_b(const int* __restrict__ bcur_ii, const int2* __restrict__ tmp_ii,
                       unsigned int* __restrict__ edges_ii, int* __restrict__ rp_ii,
                       int* __restrict__ rpe_ii, int nb_ii,
                       const int* __restrict__ bcur_ui, const int2* __restrict__ tmp_ui,
                       unsigned int* __restrict__ edges_ui, int* __restrict__ rp_ui,
                       int* __restrict__ rpe_ui) {
    __shared__ int cnt[RPB];
    __shared__ int cur[RPB];
    __shared__ int sc[RPB];
    const bool is_ii = (blockIdx.x < (unsigned)nb_ii);
    const int b = is_ii ? blockIdx.x : (blockIdx.x - nb_ii);
    const int* __restrict__ bcur = is_ii ? bcur_ii : bcur_ui;
    const int2* __restrict__ tmp = is_ii ? tmp_ii : tmp_ui;
    unsigned int* __restrict__ edges = is_ii ? edges_ii : edges_ui;
    int* __restrict__ rp  = is_ii ? rp_ii : rp_ui;
    int* __restrict__ rpe = is_ii ? rpe_ii : rpe_ui;
    const int n_rows = is_ii ? MM : UU;
    const int cap_tmp = is_ii ? CAP_II : CAP_UI;
    const int cap_e   = is_ii ? CAPE_II : CAPE_UI;

    int t = threadIdx.x;
    int ebeg = b * cap_e;
    if (t < RPB) cnt[t] = 0;
    __syncthreads();
    for (int k = 0; k < KSUB; k++) {
        int sb = b * cap_tmp + k * (cap_tmp >> 3);
        int se = sb + bcur[b * KSUB + k] * 8;
        for (int i = sb + t; i < se; i += blockDim.x) {
            int xw = tmp[i].x;
            if (xw != -1) atomicAdd(&cnt[(xw >> 17) & (RPB - 1)], 1);
        }
    }
    __syncthreads();
    int v = 0;
    if (t < RPB) { v = cnt[t]; sc[t] = v; }
    __syncthreads();
    for (int off = 1; off < RPB; off <<= 1) {
        int u = 0;
        if (t < RPB && t >= off) u = sc[t - off];
        __syncthreads();
        if (t < RPB) sc[t] += u;
        __syncthreads();
    }
    if (t < RPB) {
        int excl = sc[t] - v;
        int r = (b << BSH) + t;
        if (r < n_rows) { rp[r] = ebeg + excl; rpe[r] = ebeg + excl + v; }
        cur[t] = ebeg + excl;
    }
    __syncthreads();
    for (int k = 0; k < KSUB; k++) {
        int sb = b * cap_tmp + k * (cap_tmp >> 3);
        int se = sb + bcur[b * KSUB + k] * 8;
        for (int i = sb + t; i < se; i += blockDim.x) {
            int2 e = tmp[i];
            if (e.x == -1) continue;
            int s = (e.x >> 17) & (RPB - 1);
            int pos = atomicAdd(&cur[s], 1);
            unsigned int vb = f2bf(__int_as_float(e.y)) & 0x7FFFu;
            edges[pos] = ((unsigned int)(e.x & 0x1FFFF) << 15) | vb;
        }
    }
}

// ---- fp32 -> bf16 table conversion ----
__global__ void conv_bf16(const float4* __restrict__ in, ushort4* __restrict__ out, int n4) {
    int i = blockIdx.x * blockDim.x + threadIdx.x;
    if (i >= n4) return;
    float4 v = in[i];
    ushort4 o;
    o.x = f2bf(v.x); o.y = f2bf(v.y); o.z = f2bf(v.z); o.w = f2bf(v.w);
    out[i] = o;
}

// ---- propagation SpMM: DUAL-ROW quad-edge gather, bf16 acc (r13, frozen) ----
template <bool WRITE_Y, bool INIT_ACC>
__global__ void spmm_bf16(const int* __restrict__ rp, const int* __restrict__ rpe,
                          const unsigned int* __restrict__ edges,
                          const unsigned short* __restrict__ xb, unsigned short* __restrict__ yb,
                          const unsigned short* __restrict__ e0b, unsigned short* __restrict__ accb,
                          const float* __restrict__ att, int layer, int n_rows) {
    int wid = (blockIdx.x * blockDim.x + threadIdx.x) >> 6;
    int lane = threadIdx.x & 63;
    int r0 = wid * 2;
    if (r0 >= n_rows) return;
    int r1 = r0 + 1;
    bool has1 = (r1 < n_rows);
    int q = lane >> 4, sub = lane & 15;
    int eA = rp[r0], endA = rpe[r0];
    int eB = has1 ? rp[r1] : 0, endB = has1 ? rpe[r1] : 0;
    float a0 = 0.f, a1 = 0.f, a2 = 0.f, a3 = 0.f;
    float b0 = 0.f, b1 = 0.f, b2 = 0.f, b3 = 0.f;
    while (eA < endA || eB < endB) {
        unsigned int evA = 0u, evB = 0u;
        int stepsA = 0, stepsB = 0;
        if (eA < endA) {
            int idx = eA + lane;
            evA = (idx < endA) ? edges[idx] : 0u;
            stepsA = (min(64, endA - eA) + 3) >> 2;
        }
        if (eB < endB) {
            int idx = eB + lane;
            evB = (idx < endB) ? edges[idx] : 0u;
            stepsB = (min(64, endB - eB) + 3) >> 2;
        }
        int steps = max(stepsA, stepsB);
        int jq = q;
        for (int st = 0; st < steps; ++st, jq += 4) {
            unsigned int pA = (st < stepsA) ? (unsigned)__shfl((int)evA, jq, 64) : 0u;
            unsigned int pB = (st < stepsB) ? (unsigned)__shfl((int)evB, jq, 64) : 0u;
            const uint2 uA = *((const uint2*)(xb + ((size_t)pk_dst(pA) << 6)) + sub);
            const uint2 uB = *((const uint2*)(xb + ((size_t)pk_dst(pB) << 6)) + sub);
            float vA = pk_val(pA);
            float vB = pk_val(pB);
            a0 = fmaf(vA, __uint_as_float(uA.x << 16), a0);
            a1 = fmaf(vA, __uint_as_float(uA.x & 0xFFFF0000u), a1);
            a2 = fmaf(vA, __uint_as_float(uA.y << 16), a2);
            a3 = fmaf(vA, __uint_as_float(uA.y & 0xFFFF0000u), a3);
            b0 = fmaf(vB, __uint_as_float(uB.x << 16), b0);
            b1 = fmaf(vB, __uint_as_float(uB.x & 0xFFFF0000u), b1);
            b2 = fmaf(vB, __uint_as_float(uB.y << 16), b2);
            b3 = fmaf(vB, __uint_as_float(uB.y & 0xFFFF0000u), b3);
        }
        eA += 64; eB += 64;
    }
    a0 += __shfl_xor(a0, 16, 64); a0 += __shfl_xor(a0, 32, 64);
    a1 += __shfl_xor(a1, 16, 64); a1 += __shfl_xor(a1, 32, 64);
    a2 += __shfl_xor(a2, 16, 64); a2 += __shfl_xor(a2, 32, 64);
    a3 += __shfl_xor(a3, 16, 64); a3 += __shfl_xor(a3, 32, 64);
    b0 += __shfl_xor(b0, 16, 64); b0 += __shfl_xor(b0, 32, 64);
    b1 += __shfl_xor(b1, 16, 64); b1 += __shfl_xor(b1, 32, 64);
    b2 += __shfl_xor(b2, 16, 64); b2 += __shfl_xor(b2, 32, 64);
    b3 += __shfl_xor(b3, 16, 64); b3 += __shfl_xor(b3, 32, 64);
    if (lane < 32 && (lane < 16 || has1)) {
        float s0 = (lane < 16) ? a0 : b0;
        float s1 = (lane < 16) ? a1 : b1;
        float s2 = (lane < 16) ? a2 : b2;
        float s3 = (lane < 16) ? a3 : b3;
        int r = (lane < 16) ? r0 : r1;
        float a = att[layer];
        s0 *= a; s1 *= a; s2 *= a; s3 *= a;
        size_t o = (size_t)r * DD + 4 * sub;
        if (WRITE_Y) {
            ushort4 yv = make_ushort4(f2bf(s0), f2bf(s1), f2bf(s2), f2bf(s3));
            *(ushort4*)(yb + o) = yv;
        }
        const uint2 u0 = *(const uint2*)((INIT_ACC ? e0b : accb) + o);
        s0 += __uint_as_float(u0.x << 16);
        s1 += __uint_as_float(u0.x & 0xFFFF0000u);
        s2 += __uint_as_float(u0.y << 16);
        s3 += __uint_as_float(u0.y & 0xFFFF0000u);
        *(ushort4*)(accb + o) = make_ushort4(f2bf(s0), f2bf(s1), f2bf(s2), f2bf(s3));
    }
}

__global__ void set_bitmap(const int* __restrict__ users, unsigned char* __restrict__ bm, int B) {
    int i = blockIdx.x * blockDim.x + threadIdx.x;
    if (i < B) bm[users[i]] = 1;
}

// fused UI-SpMM + pair dot: quad-edge gather over bf16 acc table (frozen)
__global__ void user_dot_kernel(const int* __restrict__ users, const int* __restrict__ items,
                                const int* __restrict__ rp, const int* __restrict__ rpe,
                                const unsigned int* __restrict__ edges,
                                const unsigned short* __restrict__ accb,
                                float* __restrict__ out, int B) {
    int w = (blockIdx.x * blockDim.x + threadIdx.x) >> 6;
    int lane = threadIdx.x & 63;
    if (w >= B) return;
    int q = lane >> 4, sub = lane & 15;
    int u = users[w];
    int beg = rp[u], end = rpe[u];
    float s0 = 0.f, s1 = 0.f, s2 = 0.f, s3 = 0.f;
    for (int e = beg; e < end; e += 64) {
        int idx = e + lane;
        unsigned int ev = (idx < end) ? edges[idx] : 0u;
        int cnt = min(64, end - e);
        int steps = (cnt + 3) >> 2;
        int jq = q;
        for (int st = 0; st < steps; ++st, jq += 4) {
            unsigned int p = (unsigned)__shfl((int)ev, jq, 64);
            float v = pk_val(p);
            const uint2 x = *((const uint2*)(accb + ((size_t)pk_dst(p) << 6)) + sub);
            s0 = fmaf(v, __uint_as_float(x.x << 16), s0);
            s1 = fmaf(v, __uint_as_float(x.x & 0xFFFF0000u), s1);
            s2 = fmaf(v, __uint_as_float(x.y << 16), s2);
            s3 = fmaf(v, __uint_as_float(x.y & 0xFFFF0000u), s3);
        }
    }
    s0 += __shfl_xor(s0, 16, 64); s0 += __shfl_xor(s0, 32, 64);
    s1 += __shfl_xor(s1, 16, 64); s1 += __shfl_xor(s1, 32, 64);
    s2 += __shfl_xor(s2, 16, 64); s2 += __shfl_xor(s2, 32, 64);
    s3 += __shfl_xor(s3, 16, 64); s3 += __shfl_xor(s3, 32, 64);
    float p = 0.f;
    if (lane < 16) {
        const uint2 iu = *((const uint2*)(accb + ((size_t)items[w] << 6)) + sub);
        p = s0 * __uint_as_float(iu.x << 16)
          + s1 * __uint_as_float(iu.x & 0xFFFF0000u)
          + s2 * __uint_as_float(iu.y << 16)
          + s3 * __uint_as_float(iu.y & 0xFFFF0000u);
        #pragma unroll
        for (int m = 8; m >= 1; m >>= 1) p += __shfl_xor(p, m, 64);
        if (sub == 0) out[w] = p * 0.0625f;   // (1/4 mean) each side
    }
}

extern "C" void kernel_launch(void* const* d_in, const int* in_sizes, int n_in,
                              void* d_out, int out_size, void* d_ws, size_t ws_size,
                              hipStream_t stream) {
    const int*   users    = (const int*)d_in[0];
    const int*   items    = (const int*)d_in[1];
    const int*   ii_src   = (const int*)d_in[2];
    const int*   ii_dst   = (const int*)d_in[3];
    const float* ii_val   = (const float*)d_in[4];
    const int*   ui_src   = (const int*)d_in[5];
    const int*   ui_dst   = (const int*)d_in[6];
    const float* ui_val   = (const float*)d_in[7];
    const float* item_emb = (const float*)d_in[8];
    const float* att      = (const float*)d_in[9];

    const int E_ii = in_sizes[2];
    const int E_ui = in_sizes[5];
    const int B    = in_sizes[0];
    const int NB_ii = (MM + RPB - 1) / RPB;   // 391
    const int NB_ui = (UU + RPB - 1) / RPB;   // 196
    const int nchunks_ii = (E_ii + CHUNK - 1) / CHUNK;   // 782
    const int nchunks_ui = (E_ui + CHUNK - 1) / CHUNK;   // 391

    char* w = (char*)d_ws;
    // tmp_ii 391*13312*8 = 41,639,936; overlaid after pass_b by xb0+y1 (25.6 MB)
    int2*  tmp_ii = (int2*)(w);
    unsigned short* xb0 = (unsigned short*)(w);                   // 12.8 MB
    unsigned short* y1  = (unsigned short*)(w + 12800000);        // 12.8 MB
    // region2 @41,639,936: tmp_ui (196*4096*8 = 6,422,528) then y2 (12.8 MB)
    int2*  tmp_ui = (int2*)(w + 41639936);
    unsigned short* y2  = (unsigned short*)(w + 41639936);
    unsigned short* accb = (unsigned short*)(w + 54439936);       // 12.8 MB bf16
    unsigned int* edges_ii = (unsigned int*)(w + 67239936);       // 391*9216*4 = 14,413,824
    unsigned int* edges_ui = (unsigned int*)(w + 81653760);       // 196*2048*4 = 1,605,632
    int*   rp_ii  = (int*)(w + 83259392);                         // (MM+2)*4
    int*   rpe_ii = (int*)(w + 83659400);
    int*   rp_ui  = (int*)(w + 84059408);                         // (UU+2)*4
    int*   rpe_ui = (int*)(w + 84259416);
    int*   bcur_ii = (int*)(w + 84459424);                        // 391*8 ints (pad 4096)
    int*   bcur_ui = (int*)(w + 84475808);                        // 196*8 ints (pad 4096)
    unsigned char* bitmap = (unsigned char*)(w + 84492192);       // UU bytes

    const int TB = 256;
    const int TBB = 512;                               // build kernels
    const size_t smem_a = CHUNK * 8 + 4 * NBMAX * 4;   // 39,168 B -> 4 blocks/CU

    // ---- one memset: bcur_ii + bcur_ui + bitmap (contiguous) ----
    hipMemsetAsync(bcur_ii, 0, 2 * 4096 * sizeof(int) + UU, stream);
    set_bitmap<<<(B + TB - 1) / TB, TB, 0, stream>>>(users, bitmap, B);

    // ---- both graphs: binning + per-bucket sort in single launches ----
    pass_a<<<nchunks_ii + nchunks_ui, TBB, smem_a, stream>>>(
        ii_src, ii_dst, ii_val, bcur_ii, tmp_ii, E_ii, NB_ii, nchunks_ii,
        ui_src, ui_dst, ui_val, bcur_ui, tmp_ui, E_ui, NB_ui, bitmap);
    pass_b<<<NB_ii + NB_ui, TBB, 0, stream>>>(
        bcur_ii, tmp_ii, edges_ii, rp_ii, rpe_ii, NB_ii,
        bcur_ui, tmp_ui, edges_ui, rp_ui, rpe_ui);

    // ---- bf16 x0 (overlays tmp_ii - dead after pass_b), 3 layers ----
    const int n4 = MM * DD / 4;
    conv_bf16<<<(n4 + TB - 1) / TB, TB, 0, stream>>>((const float4*)item_emb, (ushort4*)xb0, n4);
    const int nwaves = (MM + 1) / 2;                      // dual-row waves
    const int ii_blocks = (nwaves * 64 + TB - 1) / TB;
    spmm_bf16<true,  true ><<<ii_blocks, TB, 0, stream>>>(rp_ii, rpe_ii, edges_ii, xb0, y1, xb0, accb, att, 0, MM);
    spmm_bf16<true,  false><<<ii_blocks, TB, 0, stream>>>(rp_ii, rpe_ii, edges_ii, y1,  y2, nullptr, accb, att, 1, MM);
    spmm_bf16<false, false><<<ii_blocks, TB, 0, stream>>>(rp_ii, rpe_ii, edges_ii, y2,  nullptr, nullptr, accb, att, 2, MM);

    // ---- fused user aggregation + pair dot ----
    user_dot_kernel<<<(B * 64 + TB - 1) / TB, TB, 0, stream>>>(users, items, rp_ui, rpe_ui, edges_ui, accb,
                                                               (float*)d_out, B);
}

// Round 18
// 392.690 us; speedup vs baseline: 1.0452x; 1.0452x over previous
//
#include <hip/hip_runtime.h>

// LightGCN on MI355X, round 18.
// r1..r13: gather CSR + bf16 tables + quad-edge dual-row gather -> 419.
// r14: concurrent builds -> 410. r15: FAILED (cap sized at wrong granularity).
// r16: 407. r17: sub-cursors -> 410 (no gain). pass_a pinned at ~95 us across
//      Occ 26->53% and chain depth 782->98: it is WRITE-PATTERN bound - ~10-edge
//      (84 B) bursts scattered over 41 MB => random-64B-write DRAM locality,
//      0.9-1.3 TB/s effective in every variant.
// r18: sequential-write build. pass_a: bin chunk in LDS, write block-contiguous
//      region (no padding/reservation/markers) + lbase table. pass_b: block =
//      128-row bucket, gathers segments from all chunks via table (random READS
//      overlap fine), LDS sort, ONE sequential output burst. Caps: II stage
//      4608 vs fill 4092 (8 sigma edge-level); UI 1024 vs 322 (6.9 sigma
//      user-level per r15 rule).

#define MM 100000
#define UU 50000
#define DD 64
#define RPB 128           // rows per bucket
#define BSH 7
#define NBMAX 800
#define CHUNK 4096
#define STAGE_B 4608      // pass_b stage entries (= CAPE_II)
#define CAPE_II 4608      // edges stride II
#define CAPE_UI 1024      // edges stride UI

__device__ __forceinline__ unsigned short f2bf(float f) {
    unsigned int b = __float_as_uint(f);
    b += 0x7FFF + ((b >> 16) & 1);          // round-to-nearest-even
    return (unsigned short)(b >> 16);
}
// packed edge: (dst << 15) | (bf16(val) & 0x7FFF); val >= 0 so sign bit unused
__device__ __forceinline__ float pk_val(unsigned int w) {
    return __uint_as_float((w & 0x7FFFu) << 16);
}
__device__ __forceinline__ int pk_dst(unsigned int w) { return (int)(w >> 15); }

// ---- pass A: LDS binning, block-contiguous sequential flush + offset table ----
// tmp entry: dst | (src & 127) << 17 ; tab row c: exclusive bucket offsets [nb+1]
__global__ void pass_a(const int* __restrict__ src_ii, const int* __restrict__ dst_ii,
                       const float* __restrict__ val_ii, int2* __restrict__ tmp_ii,
                       int* __restrict__ tab_ii, int nnz_ii, int nb_ii, int nchunks_ii,
                       const int* __restrict__ src_ui, const int* __restrict__ dst_ui,
                       const float* __restrict__ val_ui, int2* __restrict__ tmp_ui,
                       int* __restrict__ tab_ui, int nnz_ui, int nb_ui,
                       const unsigned char* __restrict__ filter) {
    extern __shared__ char smem[];
    int2* stage = (int2*)smem;                     // CHUNK entries (32 KB)
    int*  lcnt  = (int*)(smem + CHUNK * 8);        // NBMAX
    int*  lbase = lcnt + NBMAX;                    // NBMAX+1
    int*  lcur  = lbase + NBMAX + 1;               // NBMAX
    const bool is_ii = (blockIdx.x < (unsigned)nchunks_ii);
    const int chunk_id = is_ii ? blockIdx.x : (blockIdx.x - nchunks_ii);
    const int* __restrict__ src = is_ii ? src_ii : src_ui;
    const int* __restrict__ dst = is_ii ? dst_ii : dst_ui;
    const float* __restrict__ val = is_ii ? val_ii : val_ui;
    int2* __restrict__ tmp = is_ii ? tmp_ii : tmp_ui;
    int*  __restrict__ tab = is_ii ? tab_ii : tab_ui;
    const int nnz = is_ii ? nnz_ii : nnz_ui;
    const int nb  = is_ii ? nb_ii : nb_ui;
    const unsigned char* __restrict__ flt = is_ii ? nullptr : filter;

    int t = threadIdx.x;
    for (int i = t; i < nb; i += blockDim.x) lcnt[i] = 0;
    __syncthreads();
    int beg = chunk_id * CHUNK, end = min(nnz, beg + CHUNK);
    for (int i = beg + t; i < end; i += blockDim.x) {
        int s = src[i];
        if (flt && !flt[s]) continue;
        atomicAdd(&lcnt[s >> BSH], 1);
    }
    __syncthreads();
    // wave 0: exclusive scan lcnt -> lbase[0..nb], lbase[nb] = total
    if (t < 64) {
        int carry = 0;
        for (int g = 0; g < nb; g += 64) {
            int i = g + t;
            int v = (i < nb) ? lcnt[i] : 0;
            int incl = v;
            #pragma unroll
            for (int m = 1; m < 64; m <<= 1) {
                int u = __shfl_up(incl, m, 64);
                if (t >= m) incl += u;
            }
            if (i < nb) lbase[i] = carry + incl - v;
            carry += __shfl(incl, 63, 64);
        }
        if (t == 0) lbase[nb] = carry;
    }
    __syncthreads();
    for (int i = t; i < nb; i += blockDim.x) lcur[i] = lbase[i];
    __syncthreads();
    // bin into LDS stage
    for (int i = beg + t; i < end; i += blockDim.x) {
        int s = src[i];
        if (flt && !flt[s]) continue;
        int b = s >> BSH;
        int pos = atomicAdd(&lcur[b], 1);
        stage[pos] = make_int2(dst[i] | ((s & (RPB - 1)) << 17), __float_as_int(val[i]));
    }
    __syncthreads();
    // SEQUENTIAL flush: block-contiguous region + table row
    int total = lbase[nb];
    int2* outp = tmp + (size_t)chunk_id * CHUNK;
    for (int i = t; i < total; i += blockDim.x) outp[i] = stage[i];
    int* trow = tab + (size_t)chunk_id * (nb + 1);
    for (int i = t; i <= nb; i += blockDim.x) trow[i] = lbase[i];
}

// ---- pass B: block = bucket; gather segments via table, LDS sort, sequential write ----
__global__ void pass_b(const int2* __restrict__ tmp_ii, const int* __restrict__ tab_ii,
                       int nch_ii, unsigned int* __restrict__ edges_ii,
                       int* __restrict__ rp_ii, int* __restrict__ rpe_ii, int nb_ii,
                       const int2* __restrict__ tmp_ui, const int* __restrict__ tab_ui,
                       int nch_ui, unsigned int* __restrict__ edges_ui,
                       int* __restrict__ rp_ui, int* __restrict__ rpe_ui) {
    __shared__ int2 stage[STAGE_B];            // 36,864 B
    __shared__ unsigned int outs[STAGE_B];     // 18,432 B
    __shared__ int tsum[512];
    __shared__ int cnt[RPB];
    __shared__ int cur[RPB];
    __shared__ int sc[RPB];
    const bool is_ii = (blockIdx.x < (unsigned)nb_ii);
    const int b = is_ii ? blockIdx.x : (blockIdx.x - nb_ii);
    const int2* __restrict__ tmp = is_ii ? tmp_ii : tmp_ui;
    const int* __restrict__ tab = is_ii ? tab_ii : tab_ui;
    unsigned int* __restrict__ edges = is_ii ? edges_ii : edges_ui;
    int* __restrict__ rp  = is_ii ? rp_ii : rp_ui;
    int* __restrict__ rpe = is_ii ? rpe_ii : rpe_ui;
    const int nch = is_ii ? nch_ii : nch_ui;
    const int nbp1 = (is_ii ? nb_ii : (gridDim.x - nb_ii)) + 1;
    const int n_rows = is_ii ? MM : UU;
    const int cap_e = is_ii ? CAPE_II : CAPE_UI;

    int t = threadIdx.x;
    // phase 0: per-thread segment-length sums over assigned chunks
    int mysum = 0;
    for (int c = t; c < nch; c += 512)
        mysum += tab[(size_t)c * nbp1 + b + 1] - tab[(size_t)c * nbp1 + b];
    tsum[t] = mysum;
    __syncthreads();
    for (int off = 1; off < 512; off <<= 1) {
        int u = (t >= off) ? tsum[t - off] : 0;
        __syncthreads();
        tsum[t] += u;
        __syncthreads();
    }
    int mybase = tsum[t] - mysum;
    int total = tsum[511];
    // phase 1: gather segments into LDS stage (random ~84B reads, high MLP)
    for (int c = t; c < nch; c += 512) {
        int s0 = tab[(size_t)c * nbp1 + b];
        int s1 = tab[(size_t)c * nbp1 + b + 1];
        const int2* seg = tmp + (size_t)c * CHUNK + s0;
        for (int k = 0; k < s1 - s0; k++) stage[mybase++] = seg[k];
    }
    __syncthreads();
    // phase 2: row hist -> scan -> rp/rpe -> scatter to LDS out -> sequential store
    if (t < RPB) cnt[t] = 0;
    __syncthreads();
    for (int i = t; i < total; i += 512)
        atomicAdd(&cnt[(stage[i].x >> 17) & (RPB - 1)], 1);
    __syncthreads();
    int v = 0;
    if (t < RPB) { v = cnt[t]; sc[t] = v; }
    __syncthreads();
    for (int off = 1; off < RPB; off <<= 1) {
        int u = 0;
        if (t < RPB && t >= off) u = sc[t - off];
        __syncthreads();
        if (t < RPB) sc[t] += u;
        __syncthreads();
    }
    int ebeg = b * cap_e;
    if (t < RPB) {
        int excl = sc[t] - v;
        int r = (b << BSH) + t;
        if (r < n_rows) { rp[r] = ebeg + excl; rpe[r] = ebeg + excl + v; }
        cur[t] = excl;
    }
    __syncthreads();
    for (int i = t; i < total; i += 512) {
        int2 e = stage[i];
        int s = (e.x >> 17) & (RPB - 1);
        int pos = atomicAdd(&cur[s], 1);
        outs[pos] = ((unsigned int)(e.x & 0x1FFFF) << 15) | (f2bf(__int_as_float(e.y)) & 0x7FFFu);
    }
    __syncthreads();
    unsigned int* eg = edges + (size_t)ebeg;
    for (int i = t; i < total; i += 512) eg[i] = outs[i];
}

// ---- fp32 -> bf16 table conversion ----
__global__ void conv_bf16(const float4* __restrict__ in, ushort4* __restrict__ out, int n4) {
    int i = blockIdx.x * blockDim.x + threadIdx.x;
    if (i >= n4) return;
    float4 v = in[i];
    ushort4 o;
    o.x = f2bf(v.x); o.y = f2bf(v.y); o.z = f2bf(v.z); o.w = f2bf(v.w);
    out[i] = o;
}

// ---- propagation SpMM: DUAL-ROW quad-edge gather, bf16 acc (r13, frozen) ----
template <bool WRITE_Y, bool INIT_ACC>
__global__ void spmm_bf16(const int* __restrict__ rp, const int* __restrict__ rpe,
                          const unsigned int* __restrict__ edges,
                          const unsigned short* __restrict__ xb, unsigned short* __restrict__ yb,
                          const unsigned short* __restrict__ e0b, unsigned short* __restrict__ accb,
                          const float* __restrict__ att, int layer, int n_rows) {
    int wid = (blockIdx.x * blockDim.x + threadIdx.x) >> 6;
    int lane = threadIdx.x & 63;
    int r0 = wid * 2;
    if (r0 >= n_rows) return;
    int r1 = r0 + 1;
    bool has1 = (r1 < n_rows);
    int q = lane >> 4, sub = lane & 15;
    int eA = rp[r0], endA = rpe[r0];
    int eB = has1 ? rp[r1] : 0, endB = has1 ? rpe[r1] : 0;
    float a0 = 0.f, a1 = 0.f, a2 = 0.f, a3 = 0.f;
    float b0 = 0.f, b1 = 0.f, b2 = 0.f, b3 = 0.f;
    while (eA < endA || eB < endB) {
        unsigned int evA = 0u, evB = 0u;
        int stepsA = 0, stepsB = 0;
        if (eA < endA) {
            int idx = eA + lane;
            evA = (idx < endA) ? edges[idx] : 0u;
            stepsA = (min(64, endA - eA) + 3) >> 2;
        }
        if (eB < endB) {
            int idx = eB + lane;
            evB = (idx < endB) ? edges[idx] : 0u;
            stepsB = (min(64, endB - eB) + 3) >> 2;
        }
        int steps = max(stepsA, stepsB);
        int jq = q;
        for (int st = 0; st < steps; ++st, jq += 4) {
            unsigned int pA = (st < stepsA) ? (unsigned)__shfl((int)evA, jq, 64) : 0u;
            unsigned int pB = (st < stepsB) ? (unsigned)__shfl((int)evB, jq, 64) : 0u;
            const uint2 uA = *((const uint2*)(xb + ((size_t)pk_dst(pA) << 6)) + sub);
            const uint2 uB = *((const uint2*)(xb + ((size_t)pk_dst(pB) << 6)) + sub);
            float vA = pk_val(pA);
            float vB = pk_val(pB);
            a0 = fmaf(vA, __uint_as_float(uA.x << 16), a0);
            a1 = fmaf(vA, __uint_as_float(uA.x & 0xFFFF0000u), a1);
            a2 = fmaf(vA, __uint_as_float(uA.y << 16), a2);
            a3 = fmaf(vA, __uint_as_float(uA.y & 0xFFFF0000u), a3);
            b0 = fmaf(vB, __uint_as_float(uB.x << 16), b0);
            b1 = fmaf(vB, __uint_as_float(uB.x & 0xFFFF0000u), b1);
            b2 = fmaf(vB, __uint_as_float(uB.y << 16), b2);
            b3 = fmaf(vB, __uint_as_float(uB.y & 0xFFFF0000u), b3);
        }
        eA += 64; eB += 64;
    }
    a0 += __shfl_xor(a0, 16, 64); a0 += __shfl_xor(a0, 32, 64);
    a1 += __shfl_xor(a1, 16, 64); a1 += __shfl_xor(a1, 32, 64);
    a2 += __shfl_xor(a2, 16, 64); a2 += __shfl_xor(a2, 32, 64);
    a3 += __shfl_xor(a3, 16, 64); a3 += __shfl_xor(a3, 32, 64);
    b0 += __shfl_xor(b0, 16, 64); b0 += __shfl_xor(b0, 32, 64);
    b1 += __shfl_xor(b1, 16, 64); b1 += __shfl_xor(b1, 32, 64);
    b2 += __shfl_xor(b2, 16, 64); b2 += __shfl_xor(b2, 32, 64);
    b3 += __shfl_xor(b3, 16, 64); b3 += __shfl_xor(b3, 32, 64);
    if (lane < 32 && (lane < 16 || has1)) {
        float s0 = (lane < 16) ? a0 : b0;
        float s1 = (lane < 16) ? a1 : b1;
        float s2 = (lane < 16) ? a2 : b2;
        float s3 = (lane < 16) ? a3 : b3;
        int r = (lane < 16) ? r0 : r1;
        float a = att[layer];
        s0 *= a; s1 *= a; s2 *= a; s3 *= a;
        size_t o = (size_t)r * DD + 4 * sub;
        if (WRITE_Y) {
            ushort4 yv = make_ushort4(f2bf(s0), f2bf(s1), f2bf(s2), f2bf(s3));
            *(ushort4*)(yb + o) = yv;
        }
        const uint2 u0 = *(const uint2*)((INIT_ACC ? e0b : accb) + o);
        s0 += __uint_as_float(u0.x << 16);
        s1 += __uint_as_float(u0.x & 0xFFFF0000u);
        s2 += __uint_as_float(u0.y << 16);
        s3 += __uint_as_float(u0.y & 0xFFFF0000u);
        *(ushort4*)(accb + o) = make_ushort4(f2bf(s0), f2bf(s1), f2bf(s2), f2bf(s3));
    }
}

__global__ void set_bitmap(const int* __restrict__ users, unsigned char* __restrict__ bm, int B) {
    int i = blockIdx.x * blockDim.x + threadIdx.x;
    if (i < B) bm[users[i]] = 1;
}

// fused UI-SpMM + pair dot: quad-edge gather over bf16 acc table (frozen)
__global__ void user_dot_kernel(const int* __restrict__ users, const int* __restrict__ items,
                                const int* __restrict__ rp, const int* __restrict__ rpe,
                                const unsigned int* __restrict__ edges,
                                const unsigned short* __restrict__ accb,
                                float* __restrict__ out, int B) {
    int w = (blockIdx.x * blockDim.x + threadIdx.x) >> 6;
    int lane = threadIdx.x & 63;
    if (w >= B) return;
    int q = lane >> 4, sub = lane & 15;
    int u = users[w];
    int beg = rp[u], end = rpe[u];
    float s0 = 0.f, s1 = 0.f, s2 = 0.f, s3 = 0.f;
    for (int e = beg; e < end; e += 64) {
        int idx = e + lane;
        unsigned int ev = (idx < end) ? edges[idx] : 0u;
        int cnt = min(64, end - e);
        int steps = (cnt + 3) >> 2;
        int jq = q;
        for (int st = 0; st < steps; ++st, jq += 4) {
            unsigned int p = (unsigned)__shfl((int)ev, jq, 64);
            float v = pk_val(p);
            const uint2 x = *((const uint2*)(accb + ((size_t)pk_dst(p) << 6)) + sub);
            s0 = fmaf(v, __uint_as_float(x.x << 16), s0);
            s1 = fmaf(v, __uint_as_float(x.x & 0xFFFF0000u), s1);
            s2 = fmaf(v, __uint_as_float(x.y << 16), s2);
            s3 = fmaf(v, __uint_as_float(x.y & 0xFFFF0000u), s3);
        }
    }
    s0 += __shfl_xor(s0, 16, 64); s0 += __shfl_xor(s0, 32, 64);
    s1 += __shfl_xor(s1, 16, 64); s1 += __shfl_xor(s1, 32, 64);
    s2 += __shfl_xor(s2, 16, 64); s2 += __shfl_xor(s2, 32, 64);
    s3 += __shfl_xor(s3, 16, 64); s3 += __shfl_xor(s3, 32, 64);
    float p = 0.f;
    if (lane < 16) {
        const uint2 iu = *((const uint2*)(accb + ((size_t)items[w] << 6)) + sub);
        p = s0 * __uint_as_float(iu.x << 16)
          + s1 * __uint_as_float(iu.x & 0xFFFF0000u)
          + s2 * __uint_as_float(iu.y << 16)
          + s3 * __uint_as_float(iu.y & 0xFFFF0000u);
        #pragma unroll
        for (int m = 8; m >= 1; m >>= 1) p += __shfl_xor(p, m, 64);
        if (sub == 0) out[w] = p * 0.0625f;   // (1/4 mean) each side
    }
}

extern "C" void kernel_launch(void* const* d_in, const int* in_sizes, int n_in,
                              void* d_out, int out_size, void* d_ws, size_t ws_size,
                              hipStream_t stream) {
    const int*   users    = (const int*)d_in[0];
    const int*   items    = (const int*)d_in[1];
    const int*   ii_src   = (const int*)d_in[2];
    const int*   ii_dst   = (const int*)d_in[3];
    const float* ii_val   = (const float*)d_in[4];
    const int*   ui_src   = (const int*)d_in[5];
    const int*   ui_dst   = (const int*)d_in[6];
    const float* ui_val   = (const float*)d_in[7];
    const float* item_emb = (const float*)d_in[8];
    const float* att      = (const float*)d_in[9];

    const int E_ii = in_sizes[2];
    const int E_ui = in_sizes[5];
    const int B    = in_sizes[0];
    const int NB_ii = (MM + RPB - 1) / RPB;              // 782
    const int NB_ui = (UU + RPB - 1) / RPB;              // 391
    const int nchunks_ii = (E_ii + CHUNK - 1) / CHUNK;   // 782
    const int nchunks_ui = (E_ui + CHUNK - 1) / CHUNK;   // 391

    char* w = (char*)d_ws;
    // tmp_ii 782*4096*8 = 25,624,576; overlaid after pass_b by xb0+y1 (25.6 MB)
    int2*  tmp_ii = (int2*)(w);
    unsigned short* xb0 = (unsigned short*)(w);                   // 12.8 MB
    unsigned short* y1  = (unsigned short*)(w + 12800000);        // 12.8 MB
    // tmp_ui 391*4096*8 = 12,812,288 @25,624,576; overlaid by y2 (12.8 MB)
    int2*  tmp_ui = (int2*)(w + 25624576);
    unsigned short* y2  = (unsigned short*)(w + 25624576);
    unsigned short* accb = (unsigned short*)(w + 38436864);       // 12.8 MB bf16
    unsigned int* edges_ii = (unsigned int*)(w + 51236864);       // 782*4608*4 = 14,413,824
    unsigned int* edges_ui = (unsigned int*)(w + 65650688);       // 391*1024*4 = 1,601,536
    int*   tab_ii = (int*)(w + 67252224);                         // 782*783*4 = 2,449,224
    int*   tab_ui = (int*)(w + 69701448);                         // 391*392*4 = 613,088
    int*   rp_ii  = (int*)(w + 70314536);                         // (MM+2)*4
    int*   rpe_ii = (int*)(w + 70714544);
    int*   rp_ui  = (int*)(w + 71114552);                         // (UU+2)*4
    int*   rpe_ui = (int*)(w + 71314560);
    unsigned char* bitmap = (unsigned char*)(w + 71514568);       // UU bytes

    const int TB = 256;
    const int TBB = 512;
    const size_t smem_a = CHUNK * 8 + (3 * NBMAX + 8) * 4;   // ~42.4 KB -> 3 blocks/CU

    // ---- bitmap memset + set ----
    hipMemsetAsync(bitmap, 0, UU, stream);
    set_bitmap<<<(B + TB - 1) / TB, TB, 0, stream>>>(users, bitmap, B);

    // ---- both graphs: binning (sequential flush) + bucket gather/sort ----
    pass_a<<<nchunks_ii + nchunks_ui, TBB, smem_a, stream>>>(
        ii_src, ii_dst, ii_val, tmp_ii, tab_ii, E_ii, NB_ii, nchunks_ii,
        ui_src, ui_dst, ui_val, tmp_ui, tab_ui, E_ui, NB_ui, bitmap);
    pass_b<<<NB_ii + NB_ui, TBB, 0, stream>>>(
        tmp_ii, tab_ii, nchunks_ii, edges_ii, rp_ii, rpe_ii, NB_ii,
        tmp_ui, tab_ui, nchunks_ui, edges_ui, rp_ui, rpe_ui);

    // ---- bf16 x0 (overlays tmp_ii - dead after pass_b), 3 layers ----
    const int n4 = MM * DD / 4;
    conv_bf16<<<(n4 + TB - 1) / TB, TB, 0, stream>>>((const float4*)item_emb, (ushort4*)xb0, n4);
    const int nwaves = (MM + 1) / 2;                      // dual-row waves
    const int ii_blocks = (nwaves * 64 + TB - 1) / TB;
    spmm_bf16<true,  true ><<<ii_blocks, TB, 0, stream>>>(rp_ii, rpe_ii, edges_ii, xb0, y1, xb0, accb, att, 0, MM);
    spmm_bf16<true,  false><<<ii_blocks, TB, 0, stream>>>(rp_ii, rpe_ii, edges_ii, y1,  y2, nullptr, accb, att, 1, MM);
    spmm_bf16<false, false><<<ii_blocks, TB, 0, stream>>>(rp_ii, rpe_ii, edges_ii, y2,  nullptr, nullptr, accb, att, 2, MM);

    // ---- fused user aggregation + pair dot ----
    user_dot_kernel<<<(B * 64 + TB - 1) / TB, TB, 0, stream>>>(users, items, rp_ui, rpe_ui, edges_ui, accb,
                                                               (float*)d_out, B);
}